// Round 14
// baseline (303.142 us; speedup 1.0000x reference)
//
#include <hip/hip_runtime.h>
#include <hip/hip_bf16.h>
#include <stdint.h>

typedef __bf16 bf16x8 __attribute__((ext_vector_type(8)));
typedef float f32x4 __attribute__((ext_vector_type(4)));

constexpr int S = 1024, Bsz = 16, Hd = 1024;
constexpr int M = S * Bsz;   // 16384
constexpr int N = 3 * Hd;    // 3072
constexpr int K = 1024;
constexpr int BM = 128, BN = 128, BK = 32;   // BK=32 (R9-proven staging/fragments)
constexpr int NCH = 64, CS = S / NCH;  // 64 chunks x 16 steps
constexpr int BH = Bsz * Hd;           // 16384
constexpr int EP = 136;                // epilogue LDS row stride (272B, 16B-aligned)

__device__ __forceinline__ float fast_sigmoid(float x) { return 1.0f / (1.0f + __expf(-x)); }
__device__ __forceinline__ float fast_tanh(float x) { return 2.0f / (1.0f + __expf(-2.0f * x)) - 1.0f; }

// async global->LDS 16B per lane; LDS dest is wave-uniform base + lane*16
__device__ __forceinline__ void gld_lds16(const __bf16* g, __bf16* l) {
  __builtin_amdgcn_global_load_lds(
      (const __attribute__((address_space(1))) void*)g,
      (__attribute__((address_space(3))) void*)l,
      16, 0, 0);
}

// ---- fp32 -> bf16 conversion for BOTH X and W in one launch ----
__global__ void convert_all(const float* __restrict__ X, const float* __restrict__ W,
                            __bf16* __restrict__ Xb, __bf16* __restrict__ Wb) {
  int i = blockIdx.x * blockDim.x + threadIdx.x;  // 0 .. 2490367
  const float* src; __bf16* dst; int idx;
  if (i < 2097152) { src = X; dst = Xb; idx = i; }
  else             { src = W; dst = Wb; idx = i - 2097152; }
  const float4* s4 = (const float4*)src;
  float4 a = s4[2 * idx], b = s4[2 * idx + 1];
  bf16x8 v;
  v[0] = (__bf16)a.x; v[1] = (__bf16)a.y; v[2] = (__bf16)a.z; v[3] = (__bf16)a.w;
  v[4] = (__bf16)b.x; v[5] = (__bf16)b.y; v[6] = (__bf16)b.z; v[7] = (__bf16)b.w;
  *((bf16x8*)dst + idx) = v;
}

// ---- bf16 MFMA GEMM (NT: C[m,n] = sum_k A[m,k]*W[n,k]) + bias + activation ----
// RING-OF-4 counted-vmcnt pipeline (T4): iteration t stages tile t+2 into
// buf[(t+2)%4], then s_waitcnt vmcnt(8) (waits ONLY the oldest 4 loads =
// tile t's; t+1/t+2 stay in flight ACROSS the barrier), one raw s_barrier,
// compute tile t. Never vmcnt(0) in the loop.
// Race audit: stage target buffer's last reads were tile t-2, whose ds_reads
// completed (lgkm data-dep before MFMA) before the t-1 barrier; waves <=1
// barrier apart; concurrently-touched buffers distinct mod 4.
// Fully unrolled (groups of 4) -> literal LDS offsets, no pointer-swap VALU.
// R9-proven staging geometry + fragments; R3/R9-proven LDS epilogue.
__global__ __launch_bounds__(256) void gemm_act(const __bf16* __restrict__ A,
                                                const __bf16* __restrict__ Bw,
                                                const float* __restrict__ bias,
                                                __bf16* __restrict__ Y) {
  // 4 ring buffers x 8192 elems (A 4096 + B 4096) = 64KB; epilogue [128][EP]
  // = 17408 elems unions into buffers 0-2.
  __shared__ __align__(16) __bf16 smem[32768];  // 65536 B
  const int t = threadIdx.x;
  const int lane = t & 63;
  const int wave = t >> 6;
  const int wm = wave >> 1, wn = wave & 1;
  const int tn = blockIdx.x % (N / BN);   // natural order
  const int tm = blockIdx.x / (N / BN);
  const int m0 = tm * BM, n0 = tn * BN;
  const int lrow = lane & 15;
  const int quad = lane >> 4;

  // staging (R9 geometry): srow = t>>2 (0..63), 16B sub-chunk scw = t&3
  const int srow = t >> 2;
  const int scw = t & 3;
  const __bf16* gA0 = A + (size_t)(m0 + srow) * K + scw * 8;
  const __bf16* gA1 = gA0 + (size_t)64 * K;
  const __bf16* gB0 = Bw + (size_t)(n0 + srow) * K + scw * 8;
  const __bf16* gB1 = gB0 + (size_t)64 * K;
  const int wofs = wave * 512;  // wave-uniform slice

  f32x4 acc[4][4] = {};

// stage one BK=32 tile into ring buffer at elem offset OFS, advance gptrs
#define STAGE4(OFS)                                                       \
  {                                                                       \
    gld_lds16(gA0, smem + (OFS) + wofs);                                  \
    gld_lds16(gA1, smem + (OFS) + 2048 + wofs);                           \
    gld_lds16(gB0, smem + (OFS) + 4096 + wofs);                           \
    gld_lds16(gB1, smem + (OFS) + 6144 + wofs);                           \
    gA0 += BK; gA1 += BK; gB0 += BK; gB1 += BK;                           \
  }

// compute one BK=32 tile from ring buffer at elem offset OFS (R9 fragments)
#define CMP(OFS)                                                          \
  {                                                                       \
    bf16x8 af[4], bfr[4];                                                 \
    _Pragma("unroll")                                                     \
    for (int mi = 0; mi < 4; ++mi)                                        \
      af[mi] = *(const bf16x8*)(&smem[(OFS) + (wm * 64 + mi * 16 + lrow) * BK + quad * 8]); \
    _Pragma("unroll")                                                     \
    for (int ni = 0; ni < 4; ++ni)                                        \
      bfr[ni] = *(const bf16x8*)(&smem[(OFS) + 4096 + (wn * 64 + ni * 16 + lrow) * BK + quad * 8]); \
    _Pragma("unroll")                                                     \
    for (int mi = 0; mi < 4; ++mi)                                        \
      _Pragma("unroll")                                                   \
      for (int ni = 0; ni < 4; ++ni)                                      \
        acc[mi][ni] = __builtin_amdgcn_mfma_f32_16x16x32_bf16(af[mi], bfr[ni], acc[mi][ni], 0, 0, 0); \
  }

#define WAITV(NN) asm volatile("s_waitcnt vmcnt(" #NN ")" ::: "memory")
#define BAR() __builtin_amdgcn_s_barrier()

  // prologue: stage tiles 0,1 into buf0,buf1 (no wait yet)
  STAGE4(0);
  STAGE4(8192);

  // main: 7 groups of 4 K-tiles (tiles 0..27), staging tiles 2..29
#pragma unroll 1
  for (int g = 0; g < 7; ++g) {
    STAGE4(16384); WAITV(8); BAR(); CMP(0);       // t=4g+0: stage t+2 -> buf2
    STAGE4(24576); WAITV(8); BAR(); CMP(8192);    // t=4g+1: stage -> buf3
    STAGE4(0);     WAITV(8); BAR(); CMP(16384);   // t=4g+2: stage -> buf0
    STAGE4(8192);  WAITV(8); BAR(); CMP(24576);   // t=4g+3: stage -> buf1
  }
  // tail: tiles 28..31 (stage 30,31; drain 8->8->4->0)
  STAGE4(16384); WAITV(8); BAR(); CMP(0);         // t=28, stage tile30
  STAGE4(24576); WAITV(8); BAR(); CMP(8192);      // t=29, stage tile31
  WAITV(4); BAR(); CMP(16384);                    // t=30
  WAITV(0); BAR(); CMP(24576);                    // t=31

#undef STAGE4
#undef CMP
#undef WAITV
#undef BAR

  // ---- epilogue (R3/R9-proven): activation -> LDS [128][EP] -> coalesced global ----
  __syncthreads();  // full drain; smem reusable
#pragma unroll
  for (int ni = 0; ni < 4; ++ni) {
    int colL = wn * 64 + ni * 16 + lrow;
    int col = n0 + colL;
    float bv = bias[col];
    bool is_tanh = (col < Hd);
#pragma unroll
    for (int mi = 0; mi < 4; ++mi) {
#pragma unroll
      for (int r = 0; r < 4; ++r) {
        int rowL = wm * 64 + mi * 16 + quad * 4 + r;  // C/D: col=lane&15, row=quad*4+r
        float y = acc[mi][ni][r] + bv;
        float v = is_tanh ? fast_tanh(y) : fast_sigmoid(y);
        smem[rowL * EP + colL] = (__bf16)v;
      }
    }
  }
  __syncthreads();
#pragma unroll
  for (int it = 0; it < 8; ++it) {
    int slot = it * 256 + t;
    int rowL = slot >> 4;
    int cw = slot & 15;
    bf16x8 vv = *(const bf16x8*)(&smem[rowL * EP + cw * 8]);
    *(bf16x8*)(&Y[(size_t)(m0 + rowL) * N + n0 + cw * 8]) = vv;
  }
}

// ---- chunked affine scan: h_t = f*z + (1-f)*h == a*h + b, a=1-f, b=f*z ----
// pass1: per-chunk composition (A,B) (R3/R9-proven)
__global__ __launch_bounds__(256) void scan_pass1(const __bf16* __restrict__ Y,
                                                  float* __restrict__ Ac,
                                                  float* __restrict__ Bc) {
  int tid = blockIdx.x * 256 + threadIdx.x;  // 0 .. NCH*BH/8-1
  int c = tid >> 11;                          // BH/8 = 2048 threads per chunk
  int r = tid & 2047;
  int bh0 = r << 3;                           // first of 8 consecutive bh
  int b = bh0 >> 10, h0 = bh0 & (Hd - 1);
  const size_t sstep = (size_t)Bsz * N;
  size_t base0 = (size_t)b * N + h0 + (size_t)(c * CS) * sstep;
  float A[8], Bv[8];
#pragma unroll
  for (int v = 0; v < 8; ++v) { A[v] = 1.0f; Bv[v] = 0.0f; }
#pragma unroll
  for (int j0 = 0; j0 < CS; j0 += 8) {
    bf16x8 zv[8], fv[8];
#pragma unroll
    for (int j = 0; j < 8; ++j) {
      size_t base = base0 + (size_t)(j0 + j) * sstep;
      zv[j] = *(const bf16x8*)(Y + base);
      fv[j] = *(const bf16x8*)(Y + base + Hd);
    }
#pragma unroll
    for (int j = 0; j < 8; ++j) {
#pragma unroll
      for (int v = 0; v < 8; ++v) {
        float z = (float)zv[j][v], f = (float)fv[j][v];
        float a = 1.0f - f;
        Bv[v] = fmaf(a, Bv[v], f * z);
        A[v] *= a;
      }
    }
  }
  int ob = c * BH + bh0;
  f32x4 a0, a1, b0, b1;
#pragma unroll
  for (int v = 0; v < 4; ++v) { a0[v] = A[v]; a1[v] = A[v + 4]; b0[v] = Bv[v]; b1[v] = Bv[v + 4]; }
  *(f32x4*)(Ac + ob) = a0;
  *(f32x4*)(Ac + ob + 4) = a1;
  *(f32x4*)(Bc + ob) = b0;
  *(f32x4*)(Bc + ob + 4) = b1;
}

// pass2: chain chunk states; emit per-chunk h_in and C_last (R3/R9-proven)
__global__ __launch_bounds__(256) void scan_pass2(const float* __restrict__ Ac,
                                                  const float* __restrict__ Bc,
                                                  float* __restrict__ hin,
                                                  float* __restrict__ clast) {
  int bh = blockIdx.x * 256 + threadIdx.x;  // 0..BH-1
  float h = 0.0f;
#pragma unroll 8
  for (int c = 0; c < NCH; ++c) {
    hin[c * BH + bh] = h;
    h = fmaf(Ac[c * BH + bh], h, Bc[c * BH + bh]);
  }
  clast[bh] = h;
}

// pass3: replay chunk from known h_in, write Hout = o * h (R3/R9-proven)
__global__ __launch_bounds__(256) void scan_pass3(const __bf16* __restrict__ Y,
                                                  const float* __restrict__ hin,
                                                  float* __restrict__ hout) {
  int tid = blockIdx.x * 256 + threadIdx.x;
  int c = tid >> 11;
  int r = tid & 2047;
  int bh0 = r << 3;
  int b = bh0 >> 10, h0 = bh0 & (Hd - 1);
  const size_t sstep = (size_t)Bsz * N;
  size_t base0 = (size_t)b * N + h0 + (size_t)(c * CS) * sstep;
  size_t obase0 = (size_t)b * Hd + h0 + (size_t)(c * CS) * BH;
  float hp[8];
  {
    f32x4 h04 = *(const f32x4*)(hin + c * BH + bh0);
    f32x4 h14 = *(const f32x4*)(hin + c * BH + bh0 + 4);
#pragma unroll
    for (int v = 0; v < 4; ++v) { hp[v] = h04[v]; hp[v + 4] = h14[v]; }
  }
#pragma unroll
  for (int j0 = 0; j0 < CS; j0 += 8) {
    bf16x8 zv[8], fv[8], ov[8];
#pragma unroll
    for (int j = 0; j < 8; ++j) {
      size_t base = base0 + (size_t)(j0 + j) * sstep;
      zv[j] = *(const bf16x8*)(Y + base);
      fv[j] = *(const bf16x8*)(Y + base + Hd);
      ov[j] = *(const bf16x8*)(Y + base + 2 * Hd);
    }
#pragma unroll
    for (int j = 0; j < 8; ++j) {
      f32x4 o0, o1;
#pragma unroll
      for (int v = 0; v < 8; ++v) {
        float z = (float)zv[j][v], f = (float)fv[j][v], o = (float)ov[j][v];
        hp[v] = fmaf(f, z - hp[v], hp[v]);  // f*z + (1-f)*h
        float out = o * hp[v];
        if (v < 4) o0[v] = out; else o1[v - 4] = out;
      }
      size_t ob = obase0 + (size_t)(j0 + j) * BH;
      *(f32x4*)(hout + ob) = o0;
      *(f32x4*)(hout + ob + 4) = o1;
    }
  }
}

extern "C" void kernel_launch(void* const* d_in, const int* in_sizes, int n_in,
                              void* d_out, int out_size, void* d_ws, size_t ws_size,
                              hipStream_t stream) {
  const float* X = (const float*)d_in[0];    // [1024,16,1024]
  const float* W = (const float*)d_in[1];    // [3072,1024]
  const float* bias = (const float*)d_in[2]; // [3072]
  float* out = (float*)d_out;                // Hout (16777216) + C_last (16384)

  char* ws = (char*)d_ws;
  __bf16* Xb = (__bf16*)ws;                      // 33,554,432 B
  __bf16* Wb = (__bf16*)(ws + 33554432);         // 6,291,456 B
  __bf16* Yv = (__bf16*)(ws + 39845888);         // 100,663,296 B (bf16 Y)
  float* Ac = (float*)(ws + 39845888 + 100663296);
  float* Bc = Ac + NCH * BH;                     // 4 MB each (NCH=64)
  float* hin = Bc + NCH * BH;

  convert_all<<<9728, 256, 0, stream>>>(X, W, Xb, Wb);

  dim3 ggrid((M / BM) * (N / BN));   // 3072
  dim3 vgrid(NCH * BH / 8 / 256);    // 512 blocks
  gemm_act<<<ggrid, 256, 0, stream>>>(Xb, Wb, bias, Yv);
  scan_pass1<<<vgrid, 256, 0, stream>>>(Yv, Ac, Bc);
  scan_pass2<<<BH / 256, 256, 0, stream>>>(Ac, Bc, hin, out + 16777216);
  scan_pass3<<<vgrid, 256, 0, stream>>>(Yv, hin, out);
}